// Round 5
// baseline (215.856 us; speedup 1.0000x reference)
//
#include <hip/hip_runtime.h>
#include <math.h>

#define ALPHA 0.75f

// Only bins 5..9 carry loss (loss > 0  <=>  x > 0  <=>  g > 0.5), so only 5
// cumulative thresholds are needed. logit(k/10) for k = 5..9:
#define L5 0.0f
#define L6 0.40546510810816444f
#define L7 0.8472978603872037f
#define L8 1.3862943611198906f
#define L9 2.1972245773362196f

__global__ __launch_bounds__(256) void ghm_hist_kernel(
        const float4* __restrict__ v1, const float4* __restrict__ v2,
        const float4* __restrict__ vt,
        const float* __restrict__ o1, const float* __restrict__ o2,
        const float* __restrict__ tg,
        unsigned int* __restrict__ g_cc, float* __restrict__ g_ss,
        int n) {
    unsigned int cc0 = 0, cc1 = 0, cc2 = 0, cc3 = 0, cc4 = 0;
    float        ss0 = 0, ss1 = 0, ss2 = 0, ss3 = 0, ss4 = 0;

    auto elem = [&](float x1, float x2, float t) {
        float diff = x1 - x2;
        float es   = __builtin_fmaf(2.0f, t, -1.0f);   // reference quirk: {-3,+1}
        float x    = -diff * es;                       // sigmoid argument
        float loss = fmaxf(0.0f, -t * diff);           // MARGIN = 0
        // each threshold: v_cmp -> vcc reused by addc (count) and cndmask (sum)
        cc0 += (x >= L5);  ss0 += (x >= L5) ? loss : 0.0f;
        cc1 += (x >= L6);  ss1 += (x >= L6) ? loss : 0.0f;
        cc2 += (x >= L7);  ss2 += (x >= L7) ? loss : 0.0f;
        cc3 += (x >= L8);  ss3 += (x >= L8) ? loss : 0.0f;
        cc4 += (x >= L9);  ss4 += (x >= L9) ? loss : 0.0f;
    };
    auto quad = [&](const float4& a, const float4& b, const float4& t) {
        elem(a.x, b.x, t.x); elem(a.y, b.y, t.y);
        elem(a.z, b.z, t.z); elem(a.w, b.w, t.w);
    };

    const int n4     = n >> 2;
    const int idx    = blockIdx.x * blockDim.x + threadIdx.x;
    const int stride = gridDim.x * blockDim.x;

    if (idx < n4) {
        // Software pipeline, register double-buffer (static names only).
        // Loads for step k+1 are issued before computing step k, keeping
        // ~6 dwordx4 loads in flight across the compute phase.
        const int K = 1 + (n4 - 1 - idx) / stride;     // triples for this thread
        float4 Aa, Ab, At, Ba, Bb, Bt;
        int i = idx;
        Aa = v1[i]; Ab = v2[i]; At = vt[i];
        int k = 0;
        while (k + 2 <= K - 1) {
            const int i1 = i + stride;
            Ba = v1[i1]; Bb = v2[i1]; Bt = vt[i1];     // prefetch k+1
            quad(Aa, Ab, At);                          // compute k
            const int i2 = i1 + stride;
            Aa = v1[i2]; Ab = v2[i2]; At = vt[i2];     // prefetch k+2
            quad(Ba, Bb, Bt);                          // compute k+1
            i = i2;
            k += 2;
        }
        if (k < K - 1) {                               // one step left to load
            const int i1 = i + stride;
            Ba = v1[i1]; Bb = v2[i1]; Bt = vt[i1];
            quad(Aa, Ab, At);
            quad(Ba, Bb, Bt);
        } else {
            quad(Aa, Ab, At);
        }
    }

    // scalar tail (n % 4 != 0; not hit for N = 2^24)
    const int tail_base = n4 << 2;
    if (idx < n - tail_base) {
        elem(o1[tail_base + idx], o2[tail_base + idx], tg[tail_base + idx]);
    }

    // Wave-level butterfly reduction (64 lanes), 10 quantities.
    float sv[5] = {ss0, ss1, ss2, ss3, ss4};
    unsigned int cv[5] = {cc0, cc1, cc2, cc3, cc4};
#pragma unroll
    for (int q = 0; q < 5; ++q) {
        unsigned int c = cv[q];
        float        s = sv[q];
#pragma unroll
        for (int off = 32; off > 0; off >>= 1) {
            c += __shfl_down(c, off, 64);
            s += __shfl_down(s, off, 64);
        }
        cv[q] = c; sv[q] = s;
    }

    // Cross-wave reduction via LDS (4 waves / block), then one atomic per bin.
    __shared__ unsigned int lc[4][5];
    __shared__ float        ls[4][5];
    const int wave = threadIdx.x >> 6;
    const int lane = threadIdx.x & 63;
    if (lane == 0) {
#pragma unroll
        for (int q = 0; q < 5; ++q) { lc[wave][q] = cv[q]; ls[wave][q] = sv[q]; }
    }
    __syncthreads();
    if (threadIdx.x < 5) {
        unsigned int c = 0u;
#pragma unroll
        for (int w = 0; w < 4; ++w) c += lc[w][threadIdx.x];
        atomicAdd(&g_cc[threadIdx.x], c);
    } else if (threadIdx.x >= 16 && threadIdx.x < 21) {
        const int q = threadIdx.x - 16;
        float s = 0.0f;
#pragma unroll
        for (int w = 0; w < 4; ++w) s += ls[w][q];
        atomicAdd(&g_ss[q], s);
    }
}

__global__ void ghm_final_kernel(const unsigned int* __restrict__ g_cc,
                                 const float* __restrict__ g_ss,
                                 float* __restrict__ out, int n) {
    if (threadIdx.x == 0 && blockIdx.x == 0) {
        float tot[5], s[5];
#pragma unroll
        for (int j = 0; j < 4; ++j) {
            tot[j] = (float)(g_cc[j] - g_cc[j + 1]);
            s[j]   = g_ss[j] - g_ss[j + 1];
        }
        tot[4] = (float)g_cc[4];
        s[4]   = g_ss[4];
        float acc = 0.0f;
#pragma unroll
        for (int j = 0; j < 5; ++j) {
            acc += s[j] * powf(fmaxf(tot[j], 1.0f), -ALPHA);
        }
        out[0] = acc / (float)n;
    }
}

extern "C" void kernel_launch(void* const* d_in, const int* in_sizes, int n_in,
                              void* d_out, int out_size, void* d_ws, size_t ws_size,
                              hipStream_t stream) {
    const float* o1 = (const float*)d_in[0];
    const float* o2 = (const float*)d_in[1];
    const float* tg = (const float*)d_in[2];
    float* out = (float*)d_out;
    const int n = in_sizes[0];

    unsigned int* g_cc = (unsigned int*)d_ws;                         // 5 u32
    float* g_ss = (float*)((char*)d_ws + 8 * sizeof(unsigned int));   // 5 f32

    // Workspace is re-poisoned to 0xAA before every timed call — zero it.
    hipMemsetAsync(d_ws, 0, 16 * sizeof(unsigned int), stream);

    const int block = 256;
    const int n4 = n >> 2;
    int grid = (n4 + block - 1) / block;
    if (grid < 1) grid = 1;
    if (grid > 2048) grid = 2048;

    ghm_hist_kernel<<<grid, block, 0, stream>>>(
        (const float4*)o1, (const float4*)o2, (const float4*)tg,
        o1, o2, tg, g_cc, g_ss, n);
    ghm_final_kernel<<<1, 64, 0, stream>>>(g_cc, g_ss, out, n);
}

// Round 6
// 209.694 us; speedup vs baseline: 1.0294x; 1.0294x over previous
//
#include <hip/hip_runtime.h>
#include <math.h>

#define ALPHA 0.75f

// Only bins 5..9 carry loss (loss > 0 <=> x > 0 <=> g > 0.5), so only 5
// cumulative thresholds are needed. logit(k/10) for k = 5..9:
#define L5 0.0f
#define L6 0.40546510810816444f
#define L7 0.8472978603872037f
#define L8 1.3862943611198906f
#define L9 2.1972245773362196f

__global__ __launch_bounds__(256) void ghm_hist_kernel(
        const float4* __restrict__ v1, const float4* __restrict__ v2,
        const float4* __restrict__ vt,
        unsigned int* __restrict__ g_cc, float* __restrict__ g_ss,
        int n) {
    unsigned int cc0 = 0, cc1 = 0, cc2 = 0, cc3 = 0, cc4 = 0;
    float        ss0 = 0, ss1 = 0, ss2 = 0, ss3 = 0, ss4 = 0;

    auto elem = [&](float x1, float x2, float t) {
        float diff = x1 - x2;
        float es   = __builtin_fmaf(2.0f, t, -1.0f);   // reference quirk: {-3,+1}
        float x    = -diff * es;                       // sigmoid argument
        float loss = fmaxf(0.0f, -t * diff);           // MARGIN = 0
        cc0 += (x >= L5);  ss0 += (x >= L5) ? loss : 0.0f;
        cc1 += (x >= L6);  ss1 += (x >= L6) ? loss : 0.0f;
        cc2 += (x >= L7);  ss2 += (x >= L7) ? loss : 0.0f;
        cc3 += (x >= L8);  ss3 += (x >= L8) ? loss : 0.0f;
        cc4 += (x >= L9);  ss4 += (x >= L9) ? loss : 0.0f;
    };
    auto quad = [&](const float4& a, const float4& b, const float4& t) {
        elem(a.x, b.x, t.x); elem(a.y, b.y, t.y);
        elem(a.z, b.z, t.z); elem(a.w, b.w, t.w);
    };

    const int n4     = n >> 2;
    const int idx    = blockIdx.x * blockDim.x + threadIdx.x;
    const int stride = gridDim.x * blockDim.x;

    // 4x-unrolled grid-stride loop: all 12 dwordx4 loads issued back-to-back
    // before any compute -> compiler emits partial vmcnt waits, ~12 loads in
    // flight per thread. Simple structure (round-3 style) — no explicit
    // pipeline, which regressed in round 5.
    int i = idx;
    for (; i + 3 * stride < n4; i += 4 * stride) {
        const int i1 = i + stride, i2 = i + 2 * stride, i3 = i + 3 * stride;
        float4 a0 = v1[i];  float4 b0 = v2[i];  float4 t0 = vt[i];
        float4 a1 = v1[i1]; float4 b1 = v2[i1]; float4 t1 = vt[i1];
        float4 a2 = v1[i2]; float4 b2 = v2[i2]; float4 t2 = vt[i2];
        float4 a3 = v1[i3]; float4 b3 = v2[i3]; float4 t3 = vt[i3];
        quad(a0, b0, t0);
        quad(a1, b1, t1);
        quad(a2, b2, t2);
        quad(a3, b3, t3);
    }
    for (; i < n4; i += stride) {
        float4 a0 = v1[i]; float4 b0 = v2[i]; float4 t0 = vt[i];
        quad(a0, b0, t0);
    }
    // scalar tail (n % 4 != 0; not hit for N = 2^24)
    const int tail_base = n4 << 2;
    if (idx < n - tail_base) {
        const float* o1 = (const float*)v1;
        const float* o2 = (const float*)v2;
        const float* tg = (const float*)vt;
        elem(o1[tail_base + idx], o2[tail_base + idx], tg[tail_base + idx]);
    }

    // Wave-level butterfly reduction (64 lanes), 10 quantities.
    float sv[5] = {ss0, ss1, ss2, ss3, ss4};
    unsigned int cv[5] = {cc0, cc1, cc2, cc3, cc4};
#pragma unroll
    for (int q = 0; q < 5; ++q) {
        unsigned int c = cv[q];
        float        s = sv[q];
#pragma unroll
        for (int off = 32; off > 0; off >>= 1) {
            c += __shfl_down(c, off, 64);
            s += __shfl_down(s, off, 64);
        }
        cv[q] = c; sv[q] = s;
    }

    // Cross-wave reduction via LDS (4 waves / block), then one atomic per bin.
    __shared__ unsigned int lc[4][5];
    __shared__ float        ls[4][5];
    const int wave = threadIdx.x >> 6;
    const int lane = threadIdx.x & 63;
    if (lane == 0) {
#pragma unroll
        for (int q = 0; q < 5; ++q) { lc[wave][q] = cv[q]; ls[wave][q] = sv[q]; }
    }
    __syncthreads();
    if (threadIdx.x < 5) {
        unsigned int c = 0u;
#pragma unroll
        for (int w = 0; w < 4; ++w) c += lc[w][threadIdx.x];
        atomicAdd(&g_cc[threadIdx.x], c);
    } else if (threadIdx.x >= 16 && threadIdx.x < 21) {
        const int q = threadIdx.x - 16;
        float s = 0.0f;
#pragma unroll
        for (int w = 0; w < 4; ++w) s += ls[w][q];
        atomicAdd(&g_ss[q], s);
    }
}

__global__ void ghm_final_kernel(const unsigned int* __restrict__ g_cc,
                                 const float* __restrict__ g_ss,
                                 float* __restrict__ out, int n) {
    if (threadIdx.x == 0 && blockIdx.x == 0) {
        float tot[5], s[5];
#pragma unroll
        for (int j = 0; j < 4; ++j) {
            tot[j] = (float)(g_cc[j] - g_cc[j + 1]);
            s[j]   = g_ss[j] - g_ss[j + 1];
        }
        tot[4] = (float)g_cc[4];
        s[4]   = g_ss[4];
        float acc = 0.0f;
#pragma unroll
        for (int j = 0; j < 5; ++j) {
            acc += s[j] * powf(fmaxf(tot[j], 1.0f), -ALPHA);
        }
        out[0] = acc / (float)n;
    }
}

extern "C" void kernel_launch(void* const* d_in, const int* in_sizes, int n_in,
                              void* d_out, int out_size, void* d_ws, size_t ws_size,
                              hipStream_t stream) {
    const float* o1 = (const float*)d_in[0];
    const float* o2 = (const float*)d_in[1];
    const float* tg = (const float*)d_in[2];
    float* out = (float*)d_out;
    const int n = in_sizes[0];

    unsigned int* g_cc = (unsigned int*)d_ws;                         // 5 u32
    float* g_ss = (float*)((char*)d_ws + 8 * sizeof(unsigned int));   // 5 f32

    // Workspace is re-poisoned to 0xAA before every timed call — zero it.
    hipMemsetAsync(d_ws, 0, 16 * sizeof(unsigned int), stream);

    const int block = 256;
    const int n4 = n >> 2;
    int grid = (n4 + block - 1) / block;
    if (grid < 1) grid = 1;
    if (grid > 2048) grid = 2048;   // 8 blocks/CU -> full 32-wave residency

    ghm_hist_kernel<<<grid, block, 0, stream>>>(
        (const float4*)o1, (const float4*)o2, (const float4*)tg,
        g_cc, g_ss, n);
    ghm_final_kernel<<<1, 64, 0, stream>>>(g_cc, g_ss, out, n);
}

// Round 7
// 207.104 us; speedup vs baseline: 1.0423x; 1.0125x over previous
//
#include <hip/hip_runtime.h>
#include <math.h>

#define ALPHA 0.75f
#define HBLOCKS 2048   // hist grid upper bound; ws layout stride

// Only bins 5..9 carry loss (loss > 0 <=> x > 0 <=> g > 0.5), so only 5
// cumulative thresholds are needed. logit(k/10) for k = 5..9:
#define L5 0.0f
#define L6 0.40546510810816444f
#define L7 0.8472978603872037f
#define L8 1.3862943611198906f
#define L9 2.1972245773362196f

// Workspace: float part[10][HBLOCKS]; quantity q<5 = cumulative count cc_q,
// q>=5 = cumulative loss sum ss_{q-5}. One slot per block -> zero contention.

__global__ __launch_bounds__(256) void ghm_hist_kernel(
        const float4* __restrict__ v1, const float4* __restrict__ v2,
        const float4* __restrict__ vt,
        float* __restrict__ ws_part, int n) {
    unsigned int cc0 = 0, cc1 = 0, cc2 = 0, cc3 = 0, cc4 = 0;
    float        ss0 = 0, ss1 = 0, ss2 = 0, ss3 = 0, ss4 = 0;

    auto elem = [&](float x1, float x2, float t) {
        float diff = x1 - x2;
        float es   = __builtin_fmaf(2.0f, t, -1.0f);   // reference quirk: {-3,+1}
        float x    = -diff * es;                       // sigmoid argument
        float loss = fmaxf(0.0f, -t * diff);           // MARGIN = 0
        cc0 += (x >= L5);  ss0 += (x >= L5) ? loss : 0.0f;
        cc1 += (x >= L6);  ss1 += (x >= L6) ? loss : 0.0f;
        cc2 += (x >= L7);  ss2 += (x >= L7) ? loss : 0.0f;
        cc3 += (x >= L8);  ss3 += (x >= L8) ? loss : 0.0f;
        cc4 += (x >= L9);  ss4 += (x >= L9) ? loss : 0.0f;
    };
    auto quad = [&](const float4& a, const float4& b, const float4& t) {
        elem(a.x, b.x, t.x); elem(a.y, b.y, t.y);
        elem(a.z, b.z, t.z); elem(a.w, b.w, t.w);
    };

    const int n4     = n >> 2;
    const int idx    = blockIdx.x * blockDim.x + threadIdx.x;
    const int stride = gridDim.x * blockDim.x;

    // r6 hot loop, unchanged: 4x-unrolled grid-stride, 12 dwordx4 loads
    // issued back-to-back before any compute.
    int i = idx;
    for (; i + 3 * stride < n4; i += 4 * stride) {
        const int i1 = i + stride, i2 = i + 2 * stride, i3 = i + 3 * stride;
        float4 a0 = v1[i];  float4 b0 = v2[i];  float4 t0 = vt[i];
        float4 a1 = v1[i1]; float4 b1 = v2[i1]; float4 t1 = vt[i1];
        float4 a2 = v1[i2]; float4 b2 = v2[i2]; float4 t2 = vt[i2];
        float4 a3 = v1[i3]; float4 b3 = v2[i3]; float4 t3 = vt[i3];
        quad(a0, b0, t0);
        quad(a1, b1, t1);
        quad(a2, b2, t2);
        quad(a3, b3, t3);
    }
    for (; i < n4; i += stride) {
        float4 a0 = v1[i]; float4 b0 = v2[i]; float4 t0 = vt[i];
        quad(a0, b0, t0);
    }
    // scalar tail (n % 4 != 0; not hit for N = 2^24)
    const int tail_base = n4 << 2;
    if (idx < n - tail_base) {
        const float* o1 = (const float*)v1;
        const float* o2 = (const float*)v2;
        const float* tg = (const float*)vt;
        elem(o1[tail_base + idx], o2[tail_base + idx], tg[tail_base + idx]);
    }

    // Wave-level butterfly reduction (64 lanes), 10 quantities.
    float sv[5] = {ss0, ss1, ss2, ss3, ss4};
    unsigned int cv[5] = {cc0, cc1, cc2, cc3, cc4};
#pragma unroll
    for (int q = 0; q < 5; ++q) {
        unsigned int c = cv[q];
        float        s = sv[q];
#pragma unroll
        for (int off = 32; off > 0; off >>= 1) {
            c += __shfl_down(c, off, 64);
            s += __shfl_down(s, off, 64);
        }
        cv[q] = c; sv[q] = s;
    }

    // Cross-wave reduction via LDS (4 waves / block), then ONE partial write
    // per quantity to a block-private slot (no atomics, no contention).
    __shared__ unsigned int lc[4][5];
    __shared__ float        ls[4][5];
    const int wave = threadIdx.x >> 6;
    const int lane = threadIdx.x & 63;
    if (lane == 0) {
#pragma unroll
        for (int q = 0; q < 5; ++q) { lc[wave][q] = cv[q]; ls[wave][q] = sv[q]; }
    }
    __syncthreads();
    if (threadIdx.x < 5) {
        unsigned int c = 0u;
#pragma unroll
        for (int w = 0; w < 4; ++w) c += lc[w][threadIdx.x];
        ws_part[threadIdx.x * HBLOCKS + blockIdx.x] = (float)c;   // counts <= 2^15, exact
    } else if (threadIdx.x >= 16 && threadIdx.x < 21) {
        const int q = threadIdx.x - 16;
        float s = 0.0f;
#pragma unroll
        for (int w = 0; w < 4; ++w) s += ls[w][q];
        ws_part[(q + 5) * HBLOCKS + blockIdx.x] = s;
    }
}

// One block, 10 waves: wave w reduces quantity w across nblocks partials,
// then thread 0 applies the GHM formula.
__global__ __launch_bounds__(640) void ghm_final_kernel(
        const float* __restrict__ ws_part, float* __restrict__ out,
        int n, int nblocks) {
    const int w    = threadIdx.x >> 6;   // 0..9
    const int lane = threadIdx.x & 63;
    float v = 0.0f;
    for (int j = lane; j < nblocks; j += 64) v += ws_part[w * HBLOCKS + j];
#pragma unroll
    for (int off = 32; off > 0; off >>= 1) v += __shfl_down(v, off, 64);
    __shared__ float sm[10];
    if (lane == 0) sm[w] = v;
    __syncthreads();
    if (threadIdx.x == 0) {
        float tot[5], s[5];
#pragma unroll
        for (int j = 0; j < 4; ++j) {
            tot[j] = sm[j] - sm[j + 1];          // per-bin counts (exact ints in f32)
            s[j]   = sm[5 + j] - sm[6 + j];      // per-bin loss sums
        }
        tot[4] = sm[4];
        s[4]   = sm[9];
        float acc = 0.0f;
#pragma unroll
        for (int j = 0; j < 5; ++j) {
            acc += s[j] * powf(fmaxf(tot[j], 1.0f), -ALPHA);
        }
        out[0] = acc / (float)n;
    }
}

extern "C" void kernel_launch(void* const* d_in, const int* in_sizes, int n_in,
                              void* d_out, int out_size, void* d_ws, size_t ws_size,
                              hipStream_t stream) {
    const float* o1 = (const float*)d_in[0];
    const float* o2 = (const float*)d_in[1];
    const float* tg = (const float*)d_in[2];
    float* out = (float*)d_out;
    const int n = in_sizes[0];

    float* ws_part = (float*)d_ws;   // 10 * HBLOCKS floats = 80 KB

    const int block = 256;
    const int n4 = n >> 2;
    int grid = (n4 + block - 1) / block;
    if (grid < 1) grid = 1;
    if (grid > HBLOCKS) grid = HBLOCKS;   // 8 blocks/CU -> full residency

    ghm_hist_kernel<<<grid, block, 0, stream>>>(
        (const float4*)o1, (const float4*)o2, (const float4*)tg,
        ws_part, n);
    ghm_final_kernel<<<1, 640, 0, stream>>>(ws_part, out, n, grid);
}

// Round 8
// 206.871 us; speedup vs baseline: 1.0434x; 1.0011x over previous
//
#include <hip/hip_runtime.h>
#include <math.h>

#define ALPHA 0.75f
#define HBLOCKS 2048   // hist grid upper bound; ws layout stride

// Only bins 5..9 carry loss (loss > 0 <=> x > 0 <=> g > 0.5), so only 5
// cumulative thresholds are needed. logit(k/10) for k = 5..9:
#define L5 0.0f
#define L6 0.40546510810816444f
#define L7 0.8472978603872037f
#define L8 1.3862943611198906f
#define L9 2.1972245773362196f

// Workspace: float part[10][HBLOCKS]; quantity q<5 = cumulative count cc_q,
// q>=5 = cumulative loss sum ss_{q-5}. One slot per block -> zero contention.

__global__ __launch_bounds__(256) void ghm_hist_kernel(
        const float4* __restrict__ v1, const float4* __restrict__ v2,
        const float4* __restrict__ vt,
        float* __restrict__ ws_part, int n, int seg) {
    unsigned int cc0 = 0, cc1 = 0, cc2 = 0, cc3 = 0, cc4 = 0;
    float        ss0 = 0, ss1 = 0, ss2 = 0, ss3 = 0, ss4 = 0;

    auto elem = [&](float x1, float x2, float t) {
        float diff = x1 - x2;
        float es   = __builtin_fmaf(2.0f, t, -1.0f);   // reference quirk: {-3,+1}
        float x    = -diff * es;                       // sigmoid argument
        float loss = fmaxf(0.0f, -t * diff);           // MARGIN = 0
        cc0 += (x >= L5);  ss0 += (x >= L5) ? loss : 0.0f;
        cc1 += (x >= L6);  ss1 += (x >= L6) ? loss : 0.0f;
        cc2 += (x >= L7);  ss2 += (x >= L7) ? loss : 0.0f;
        cc3 += (x >= L8);  ss3 += (x >= L8) ? loss : 0.0f;
        cc4 += (x >= L9);  ss4 += (x >= L9) ? loss : 0.0f;
    };
    auto quad = [&](const float4& a, const float4& b, const float4& t) {
        elem(a.x, b.x, t.x); elem(a.y, b.y, t.y);
        elem(a.z, b.z, t.z); elem(a.w, b.w, t.w);
    };

    const int n4 = n >> 2;

    // Contiguous-segment-per-block sweep (RMSNorm-shape): block b owns
    // float4 indices [b*seg, (b+1)*seg); inner stride = blockDim.x, so the
    // block reads 4KB/stream/iteration, sequentially advancing. A wave's 12
    // outstanding loads cover ADJACENT 1KB chunks instead of 8MB-separated
    // windows -> DRAM row-buffer locality. (Changed vs r7: index map only.)
    const int i0   = blockIdx.x * seg + threadIdx.x;
    const int iend = min((blockIdx.x + 1) * seg, n4);

    int i = i0;
    for (; i + 768 < iend; i += 1024) {
        const int i1 = i + 256, i2 = i + 512, i3 = i + 768;
        float4 a0 = v1[i];  float4 b0 = v2[i];  float4 t0 = vt[i];
        float4 a1 = v1[i1]; float4 b1 = v2[i1]; float4 t1 = vt[i1];
        float4 a2 = v1[i2]; float4 b2 = v2[i2]; float4 t2 = vt[i2];
        float4 a3 = v1[i3]; float4 b3 = v2[i3]; float4 t3 = vt[i3];
        quad(a0, b0, t0);
        quad(a1, b1, t1);
        quad(a2, b2, t2);
        quad(a3, b3, t3);
    }
    for (; i < iend; i += 256) {
        float4 a0 = v1[i]; float4 b0 = v2[i]; float4 t0 = vt[i];
        quad(a0, b0, t0);
    }
    // scalar tail (n % 4 != 0; not hit for N = 2^24), handled by block 0
    const int tail_base = n4 << 2;
    if (blockIdx.x == 0) {
        const int ti = tail_base + (int)threadIdx.x;
        if (ti < n) {
            const float* o1 = (const float*)v1;
            const float* o2 = (const float*)v2;
            const float* tg = (const float*)vt;
            elem(o1[ti], o2[ti], tg[ti]);
        }
    }

    // Wave-level butterfly reduction (64 lanes), 10 quantities.
    float sv[5] = {ss0, ss1, ss2, ss3, ss4};
    unsigned int cv[5] = {cc0, cc1, cc2, cc3, cc4};
#pragma unroll
    for (int q = 0; q < 5; ++q) {
        unsigned int c = cv[q];
        float        s = sv[q];
#pragma unroll
        for (int off = 32; off > 0; off >>= 1) {
            c += __shfl_down(c, off, 64);
            s += __shfl_down(s, off, 64);
        }
        cv[q] = c; sv[q] = s;
    }

    // Cross-wave reduction via LDS (4 waves / block), then ONE partial write
    // per quantity to a block-private slot (no atomics, no contention).
    __shared__ unsigned int lc[4][5];
    __shared__ float        ls[4][5];
    const int wave = threadIdx.x >> 6;
    const int lane = threadIdx.x & 63;
    if (lane == 0) {
#pragma unroll
        for (int q = 0; q < 5; ++q) { lc[wave][q] = cv[q]; ls[wave][q] = sv[q]; }
    }
    __syncthreads();
    if (threadIdx.x < 5) {
        unsigned int c = 0u;
#pragma unroll
        for (int w = 0; w < 4; ++w) c += lc[w][threadIdx.x];
        ws_part[threadIdx.x * HBLOCKS + blockIdx.x] = (float)c;   // counts <= 2^15, exact
    } else if (threadIdx.x >= 16 && threadIdx.x < 21) {
        const int q = threadIdx.x - 16;
        float s = 0.0f;
#pragma unroll
        for (int w = 0; w < 4; ++w) s += ls[w][q];
        ws_part[(q + 5) * HBLOCKS + blockIdx.x] = s;
    }
}

// One block, 10 waves: wave w reduces quantity w across nblocks partials,
// then thread 0 applies the GHM formula.
__global__ __launch_bounds__(640) void ghm_final_kernel(
        const float* __restrict__ ws_part, float* __restrict__ out,
        int n, int nblocks) {
    const int w    = threadIdx.x >> 6;   // 0..9
    const int lane = threadIdx.x & 63;
    float v = 0.0f;
    for (int j = lane; j < nblocks; j += 64) v += ws_part[w * HBLOCKS + j];
#pragma unroll
    for (int off = 32; off > 0; off >>= 1) v += __shfl_down(v, off, 64);
    __shared__ float sm[10];
    if (lane == 0) sm[w] = v;
    __syncthreads();
    if (threadIdx.x == 0) {
        float tot[5], s[5];
#pragma unroll
        for (int j = 0; j < 4; ++j) {
            tot[j] = sm[j] - sm[j + 1];          // per-bin counts (exact ints in f32)
            s[j]   = sm[5 + j] - sm[6 + j];      // per-bin loss sums
        }
        tot[4] = sm[4];
        s[4]   = sm[9];
        float acc = 0.0f;
#pragma unroll
        for (int j = 0; j < 5; ++j) {
            acc += s[j] * powf(fmaxf(tot[j], 1.0f), -ALPHA);
        }
        out[0] = acc / (float)n;
    }
}

extern "C" void kernel_launch(void* const* d_in, const int* in_sizes, int n_in,
                              void* d_out, int out_size, void* d_ws, size_t ws_size,
                              hipStream_t stream) {
    const float* o1 = (const float*)d_in[0];
    const float* o2 = (const float*)d_in[1];
    const float* tg = (const float*)d_in[2];
    float* out = (float*)d_out;
    const int n = in_sizes[0];

    float* ws_part = (float*)d_ws;   // 10 * HBLOCKS floats = 80 KB

    const int block = 256;
    const int n4 = n >> 2;
    int grid = (n4 + block - 1) / block;
    if (grid < 1) grid = 1;
    if (grid > HBLOCKS) grid = HBLOCKS;   // 8 blocks/CU -> full residency
    const int seg = (n4 + grid - 1) / grid;   // contiguous float4s per block

    ghm_hist_kernel<<<grid, block, 0, stream>>>(
        (const float4*)o1, (const float4*)o2, (const float4*)tg,
        ws_part, n, seg);
    ghm_final_kernel<<<1, 640, 0, stream>>>(ws_part, out, n, grid);
}

// Round 9
// 186.971 us; speedup vs baseline: 1.1545x; 1.1064x over previous
//
#include <hip/hip_runtime.h>
#include <math.h>

#define ALPHA 0.75f
#define HBLOCKS 2048   // hist grid upper bound; ws layout stride

// Only bins 5..9 carry loss (loss > 0 <=> x > 0 <=> g > 0.5), so only 5
// cumulative thresholds are needed. logit(k/10) for k = 5..9:
#define L5 0.0f
#define L6 0.40546510810816444f
#define L7 0.8472978603872037f
#define L8 1.3862943611198906f
#define L9 2.1972245773362196f

typedef float f4v __attribute__((ext_vector_type(4)));

// Workspace: float part[10][HBLOCKS]; q<5 = cumulative count, q>=5 = loss sum.

__global__ __launch_bounds__(256) void ghm_hist_kernel(
        const f4v* __restrict__ v1, const f4v* __restrict__ v2,
        const f4v* __restrict__ vt,
        float* __restrict__ ws_part, int n, int seg) {
    unsigned int cc0 = 0, cc1 = 0, cc2 = 0, cc3 = 0, cc4 = 0;
    float        ss0 = 0, ss1 = 0, ss2 = 0, ss3 = 0, ss4 = 0;

    auto elem = [&](float x1, float x2, float t) {
        float diff = x1 - x2;
        float es   = __builtin_fmaf(2.0f, t, -1.0f);   // reference quirk: {-3,+1}
        float x    = -diff * es;                       // sigmoid argument
        float loss = fmaxf(0.0f, -t * diff);           // MARGIN = 0
        cc0 += (x >= L5);  ss0 += (x >= L5) ? loss : 0.0f;
        cc1 += (x >= L6);  ss1 += (x >= L6) ? loss : 0.0f;
        cc2 += (x >= L7);  ss2 += (x >= L7) ? loss : 0.0f;
        cc3 += (x >= L8);  ss3 += (x >= L8) ? loss : 0.0f;
        cc4 += (x >= L9);  ss4 += (x >= L9) ? loss : 0.0f;
    };
    auto quad = [&](const f4v& a, const f4v& b, const f4v& t) {
        elem(a.x, b.x, t.x); elem(a.y, b.y, t.y);
        elem(a.z, b.z, t.z); elem(a.w, b.w, t.w);
    };

    const int n4 = n >> 2;

    // Contiguous-segment-per-block sweep (r8 mapping, unchanged).
    const int i0   = blockIdx.x * seg + threadIdx.x;
    const int iend = min((blockIdx.x + 1) * seg, n4);

    int i = i0;
    for (; i + 768 < iend; i += 1024) {
        const int i1 = i + 256, i2 = i + 512, i3 = i + 768;
        // Nontemporal (streaming) loads: single-use data, no cache allocate.
        f4v a0 = __builtin_nontemporal_load(v1 + i);
        f4v b0 = __builtin_nontemporal_load(v2 + i);
        f4v t0 = __builtin_nontemporal_load(vt + i);
        f4v a1 = __builtin_nontemporal_load(v1 + i1);
        f4v b1 = __builtin_nontemporal_load(v2 + i1);
        f4v t1 = __builtin_nontemporal_load(vt + i1);
        f4v a2 = __builtin_nontemporal_load(v1 + i2);
        f4v b2 = __builtin_nontemporal_load(v2 + i2);
        f4v t2 = __builtin_nontemporal_load(vt + i2);
        f4v a3 = __builtin_nontemporal_load(v1 + i3);
        f4v b3 = __builtin_nontemporal_load(v2 + i3);
        f4v t3 = __builtin_nontemporal_load(vt + i3);
        // Pin all 12 loads BEFORE any compute: forces the register allocator
        // to materialize 12 dwordx4 results (~48 VGPR) and gives true
        // vmcnt-depth-12 per wave. (r6/r8 compiled to VGPR=32-36 -> the
        // "batched" loads were silently serialized.)
        __builtin_amdgcn_sched_barrier(0);
        quad(a0, b0, t0);
        quad(a1, b1, t1);
        quad(a2, b2, t2);
        quad(a3, b3, t3);
    }
    for (; i < iend; i += 256) {
        f4v a0 = __builtin_nontemporal_load(v1 + i);
        f4v b0 = __builtin_nontemporal_load(v2 + i);
        f4v t0 = __builtin_nontemporal_load(vt + i);
        quad(a0, b0, t0);
    }
    // scalar tail (n % 4 != 0; not hit for N = 2^24), handled by block 0
    const int tail_base = n4 << 2;
    if (blockIdx.x == 0) {
        const int ti = tail_base + (int)threadIdx.x;
        if (ti < n) {
            const float* o1 = (const float*)v1;
            const float* o2 = (const float*)v2;
            const float* tg = (const float*)vt;
            elem(o1[ti], o2[ti], tg[ti]);
        }
    }

    // Wave-level butterfly reduction (64 lanes), 10 quantities.
    float sv[5] = {ss0, ss1, ss2, ss3, ss4};
    unsigned int cv[5] = {cc0, cc1, cc2, cc3, cc4};
#pragma unroll
    for (int q = 0; q < 5; ++q) {
        unsigned int c = cv[q];
        float        s = sv[q];
#pragma unroll
        for (int off = 32; off > 0; off >>= 1) {
            c += __shfl_down(c, off, 64);
            s += __shfl_down(s, off, 64);
        }
        cv[q] = c; sv[q] = s;
    }

    // Cross-wave reduction via LDS (4 waves / block), then ONE partial write
    // per quantity to a block-private slot (no atomics, no contention).
    __shared__ unsigned int lc[4][5];
    __shared__ float        ls[4][5];
    const int wave = threadIdx.x >> 6;
    const int lane = threadIdx.x & 63;
    if (lane == 0) {
#pragma unroll
        for (int q = 0; q < 5; ++q) { lc[wave][q] = cv[q]; ls[wave][q] = sv[q]; }
    }
    __syncthreads();
    if (threadIdx.x < 5) {
        unsigned int c = 0u;
#pragma unroll
        for (int w = 0; w < 4; ++w) c += lc[w][threadIdx.x];
        ws_part[threadIdx.x * HBLOCKS + blockIdx.x] = (float)c;   // counts exact in f32
    } else if (threadIdx.x >= 16 && threadIdx.x < 21) {
        const int q = threadIdx.x - 16;
        float s = 0.0f;
#pragma unroll
        for (int w = 0; w < 4; ++w) s += ls[w][q];
        ws_part[(q + 5) * HBLOCKS + blockIdx.x] = s;
    }
}

// One block, 10 waves: wave w reduces quantity w across nblocks partials,
// then thread 0 applies the GHM formula.
__global__ __launch_bounds__(640) void ghm_final_kernel(
        const float* __restrict__ ws_part, float* __restrict__ out,
        int n, int nblocks) {
    const int w    = threadIdx.x >> 6;   // 0..9
    const int lane = threadIdx.x & 63;
    float v = 0.0f;
    for (int j = lane; j < nblocks; j += 64) v += ws_part[w * HBLOCKS + j];
#pragma unroll
    for (int off = 32; off > 0; off >>= 1) v += __shfl_down(v, off, 64);
    __shared__ float sm[10];
    if (lane == 0) sm[w] = v;
    __syncthreads();
    if (threadIdx.x == 0) {
        float tot[5], s[5];
#pragma unroll
        for (int j = 0; j < 4; ++j) {
            tot[j] = sm[j] - sm[j + 1];          // per-bin counts (exact ints in f32)
            s[j]   = sm[5 + j] - sm[6 + j];      // per-bin loss sums
        }
        tot[4] = sm[4];
        s[4]   = sm[9];
        float acc = 0.0f;
#pragma unroll
        for (int j = 0; j < 5; ++j) {
            acc += s[j] * powf(fmaxf(tot[j], 1.0f), -ALPHA);
        }
        out[0] = acc / (float)n;
    }
}

extern "C" void kernel_launch(void* const* d_in, const int* in_sizes, int n_in,
                              void* d_out, int out_size, void* d_ws, size_t ws_size,
                              hipStream_t stream) {
    const float* o1 = (const float*)d_in[0];
    const float* o2 = (const float*)d_in[1];
    const float* tg = (const float*)d_in[2];
    float* out = (float*)d_out;
    const int n = in_sizes[0];

    float* ws_part = (float*)d_ws;   // 10 * HBLOCKS floats = 80 KB

    const int block = 256;
    const int n4 = n >> 2;
    int grid = (n4 + block - 1) / block;
    if (grid < 1) grid = 1;
    if (grid > HBLOCKS) grid = HBLOCKS;   // 8 blocks/CU -> full residency
    const int seg = (n4 + grid - 1) / grid;   // contiguous float4s per block

    ghm_hist_kernel<<<grid, block, 0, stream>>>(
        (const f4v*)o1, (const f4v*)o2, (const f4v*)tg,
        ws_part, n, seg);
    ghm_final_kernel<<<1, 640, 0, stream>>>(ws_part, out, n, grid);
}

// Round 10
// 186.301 us; speedup vs baseline: 1.1586x; 1.0036x over previous
//
#include <hip/hip_runtime.h>
#include <math.h>

#define ALPHA 0.75f
#define HBLOCKS 2048   // hist grid upper bound; ws layout stride

// Only bins 5..9 carry loss (loss > 0 <=> x > 0 <=> g > 0.5), so only 5
// cumulative thresholds are needed. logit(k/10) for k = 5..9:
#define L5 0.0f
#define L6 0.40546510810816444f
#define L7 0.8472978603872037f
#define L8 1.3862943611198906f
#define L9 2.1972245773362196f

typedef float f4v __attribute__((ext_vector_type(4)));

// Workspace: float part[10][HBLOCKS]; q<5 = cumulative count, q>=5 = loss sum.

__global__ __launch_bounds__(256) void ghm_hist_kernel(
        const f4v* __restrict__ v1, const f4v* __restrict__ v2,
        const f4v* __restrict__ vt,
        float* __restrict__ ws_part, int n, int seg) {
    unsigned int cc0 = 0, cc1 = 0, cc2 = 0, cc3 = 0, cc4 = 0;
    float        ss0 = 0, ss1 = 0, ss2 = 0, ss3 = 0, ss4 = 0;

    auto elem = [&](float x1, float x2, float t) {
        float diff = x1 - x2;
        float es   = __builtin_fmaf(2.0f, t, -1.0f);   // reference quirk: {-3,+1}
        float x    = -diff * es;                       // sigmoid argument
        float loss = fmaxf(0.0f, -t * diff);           // MARGIN = 0
        cc0 += (x >= L5);  ss0 += (x >= L5) ? loss : 0.0f;
        cc1 += (x >= L6);  ss1 += (x >= L6) ? loss : 0.0f;
        cc2 += (x >= L7);  ss2 += (x >= L7) ? loss : 0.0f;
        cc3 += (x >= L8);  ss3 += (x >= L8) ? loss : 0.0f;
        cc4 += (x >= L9);  ss4 += (x >= L9) ? loss : 0.0f;
    };
    auto quad = [&](const f4v& a, const f4v& b, const f4v& t) {
        elem(a.x, b.x, t.x); elem(a.y, b.y, t.y);
        elem(a.z, b.z, t.z); elem(a.w, b.w, t.w);
    };

    const int n4 = n >> 2;

    // Contiguous-segment-per-block sweep (r8 mapping). With grid=2048 and
    // N=2^24, seg=2048 float4s -> ONE 8-deep main iteration per thread.
    const int i0   = blockIdx.x * seg + threadIdx.x;
    const int iend = min((blockIdx.x + 1) * seg, n4);

    int i = i0;
    // 8-deep batch: 24 nt dwordx4 loads issued back-to-back, pinned ahead of
    // all compute by sched_barrier -> ~24 loads in flight per wave (r9's
    // 12-deep version was the first real win; this doubles the depth).
    for (; i + 7 * 256 < iend; i += 8 * 256) {
        f4v a0 = __builtin_nontemporal_load(v1 + i);
        f4v b0 = __builtin_nontemporal_load(v2 + i);
        f4v t0 = __builtin_nontemporal_load(vt + i);
        f4v a1 = __builtin_nontemporal_load(v1 + i + 256);
        f4v b1 = __builtin_nontemporal_load(v2 + i + 256);
        f4v t1 = __builtin_nontemporal_load(vt + i + 256);
        f4v a2 = __builtin_nontemporal_load(v1 + i + 512);
        f4v b2 = __builtin_nontemporal_load(v2 + i + 512);
        f4v t2 = __builtin_nontemporal_load(vt + i + 512);
        f4v a3 = __builtin_nontemporal_load(v1 + i + 768);
        f4v b3 = __builtin_nontemporal_load(v2 + i + 768);
        f4v t3 = __builtin_nontemporal_load(vt + i + 768);
        f4v a4 = __builtin_nontemporal_load(v1 + i + 1024);
        f4v b4 = __builtin_nontemporal_load(v2 + i + 1024);
        f4v t4 = __builtin_nontemporal_load(vt + i + 1024);
        f4v a5 = __builtin_nontemporal_load(v1 + i + 1280);
        f4v b5 = __builtin_nontemporal_load(v2 + i + 1280);
        f4v t5 = __builtin_nontemporal_load(vt + i + 1280);
        f4v a6 = __builtin_nontemporal_load(v1 + i + 1536);
        f4v b6 = __builtin_nontemporal_load(v2 + i + 1536);
        f4v t6 = __builtin_nontemporal_load(vt + i + 1536);
        f4v a7 = __builtin_nontemporal_load(v1 + i + 1792);
        f4v b7 = __builtin_nontemporal_load(v2 + i + 1792);
        f4v t7 = __builtin_nontemporal_load(vt + i + 1792);
        __builtin_amdgcn_sched_barrier(0);
        quad(a0, b0, t0);
        quad(a1, b1, t1);
        quad(a2, b2, t2);
        quad(a3, b3, t3);
        quad(a4, b4, t4);
        quad(a5, b5, t5);
        quad(a6, b6, t6);
        quad(a7, b7, t7);
    }
    // remainder: 1-deep sweep (not hit for N = 2^24 with grid = 2048)
    for (; i < iend; i += 256) {
        f4v a0 = __builtin_nontemporal_load(v1 + i);
        f4v b0 = __builtin_nontemporal_load(v2 + i);
        f4v t0 = __builtin_nontemporal_load(vt + i);
        quad(a0, b0, t0);
    }
    // scalar tail (n % 4 != 0; not hit for N = 2^24), handled by block 0
    const int tail_base = n4 << 2;
    if (blockIdx.x == 0) {
        const int ti = tail_base + (int)threadIdx.x;
        if (ti < n) {
            const float* o1 = (const float*)v1;
            const float* o2 = (const float*)v2;
            const float* tg = (const float*)vt;
            elem(o1[ti], o2[ti], tg[ti]);
        }
    }

    // Wave-level butterfly reduction (64 lanes), 10 quantities.
    float sv[5] = {ss0, ss1, ss2, ss3, ss4};
    unsigned int cv[5] = {cc0, cc1, cc2, cc3, cc4};
#pragma unroll
    for (int q = 0; q < 5; ++q) {
        unsigned int c = cv[q];
        float        s = sv[q];
#pragma unroll
        for (int off = 32; off > 0; off >>= 1) {
            c += __shfl_down(c, off, 64);
            s += __shfl_down(s, off, 64);
        }
        cv[q] = c; sv[q] = s;
    }

    // Cross-wave reduction via LDS (4 waves / block), then ONE partial write
    // per quantity to a block-private slot (no atomics, no contention).
    __shared__ unsigned int lc[4][5];
    __shared__ float        ls[4][5];
    const int wave = threadIdx.x >> 6;
    const int lane = threadIdx.x & 63;
    if (lane == 0) {
#pragma unroll
        for (int q = 0; q < 5; ++q) { lc[wave][q] = cv[q]; ls[wave][q] = sv[q]; }
    }
    __syncthreads();
    if (threadIdx.x < 5) {
        unsigned int c = 0u;
#pragma unroll
        for (int w = 0; w < 4; ++w) c += lc[w][threadIdx.x];
        ws_part[threadIdx.x * HBLOCKS + blockIdx.x] = (float)c;   // counts exact in f32
    } else if (threadIdx.x >= 16 && threadIdx.x < 21) {
        const int q = threadIdx.x - 16;
        float s = 0.0f;
#pragma unroll
        for (int w = 0; w < 4; ++w) s += ls[w][q];
        ws_part[(q + 5) * HBLOCKS + blockIdx.x] = s;
    }
}

// One block, 10 waves: wave w reduces quantity w across nblocks partials,
// then thread 0 applies the GHM formula.
__global__ __launch_bounds__(640) void ghm_final_kernel(
        const float* __restrict__ ws_part, float* __restrict__ out,
        int n, int nblocks) {
    const int w    = threadIdx.x >> 6;   // 0..9
    const int lane = threadIdx.x & 63;
    float v = 0.0f;
    for (int j = lane; j < nblocks; j += 64) v += ws_part[w * HBLOCKS + j];
#pragma unroll
    for (int off = 32; off > 0; off >>= 1) v += __shfl_down(v, off, 64);
    __shared__ float sm[10];
    if (lane == 0) sm[w] = v;
    __syncthreads();
    if (threadIdx.x == 0) {
        float tot[5], s[5];
#pragma unroll
        for (int j = 0; j < 4; ++j) {
            tot[j] = sm[j] - sm[j + 1];          // per-bin counts (exact ints in f32)
            s[j]   = sm[5 + j] - sm[6 + j];      // per-bin loss sums
        }
        tot[4] = sm[4];
        s[4]   = sm[9];
        float acc = 0.0f;
#pragma unroll
        for (int j = 0; j < 5; ++j) {
            acc += s[j] * powf(fmaxf(tot[j], 1.0f), -ALPHA);
        }
        out[0] = acc / (float)n;
    }
}

extern "C" void kernel_launch(void* const* d_in, const int* in_sizes, int n_in,
                              void* d_out, int out_size, void* d_ws, size_t ws_size,
                              hipStream_t stream) {
    const float* o1 = (const float*)d_in[0];
    const float* o2 = (const float*)d_in[1];
    const float* tg = (const float*)d_in[2];
    float* out = (float*)d_out;
    const int n = in_sizes[0];

    float* ws_part = (float*)d_ws;   // 10 * HBLOCKS floats = 80 KB

    const int block = 256;
    const int n4 = n >> 2;
    int grid = (n4 + block - 1) / block;
    if (grid < 1) grid = 1;
    if (grid > HBLOCKS) grid = HBLOCKS;   // 8 blocks/CU -> full residency
    const int seg = (n4 + grid - 1) / grid;   // contiguous float4s per block

    ghm_hist_kernel<<<grid, block, 0, stream>>>(
        (const f4v*)o1, (const f4v*)o2, (const f4v*)tg,
        ws_part, n, seg);
    ghm_final_kernel<<<1, 640, 0, stream>>>(ws_part, out, n, grid);
}